// Round 13
// baseline (133.959 us; speedup 1.0000x reference)
//
#include <hip/hip_runtime.h>
#include <math.h>

// ---------------------------------------------------------------------------
// LocalTransformerBlock2d: B=1, C=256, H=W=56 (N=3136), 8 heads x d=32,
// 7x7 local window. fp32 in/out; bf16 MFMA GEMMs.
// 3 stream-ordered kernels:
//   prep(qw cvt + LN1T) -> qkv(+pw/f1/f2 cvt blocks) -> attnmlp
// R12 FAILED: unified 96KB ring overlapped Vh [52000,103200); proj prologue
// (issued before PV) had waves 4-7 DMA-clobbering V mid-read.
// R13: proj ring-3 depth-2 confined to dead Kh (8x6KB=48KB<52KB); fc ring-6
// prologue moved AFTER the x1s barrier (all proj reads done, Vh dead).
// ---------------------------------------------------------------------------

typedef unsigned int uint;
typedef unsigned short ushort;
typedef unsigned long long u64;
typedef __attribute__((ext_vector_type(8))) short short8;   // 8 bf16
typedef __attribute__((ext_vector_type(4))) float floatx4;  // MFMA acc
typedef __attribute__((ext_vector_type(4))) unsigned short ushort4v;

#define AS1(p) (const __attribute__((address_space(1))) void*)(p)
#define AS3(p) (__attribute__((address_space(3))) void*)(p)

__device__ __forceinline__ float bf2f(ushort u) {
  union { uint i; float f; } v; v.i = ((uint)u) << 16; return v.f;
}
__device__ __forceinline__ ushort f2bf(float f) {
  union { float f; uint i; } v; v.f = f;
  uint u = v.i;
  return (ushort)((u + 0x7fffu + ((u >> 16) & 1u)) >> 16);
}

// Stage a 64-row x 256-col bf16 panel into LDS with XOR swizzle.
__device__ __forceinline__ void stage64(const ushort* src, int kstride,
                                        ushort* dstBase, int tid) {
  const int srow = tid >> 5;
  const int scb  = (tid & 31) ^ srow;
  const ushort* g = src + (size_t)srow * kstride + scb * 8;
  ushort* d = dstBase + tid * 8;
  #pragma unroll
  for (int r = 0; r < 8; ++r) {
    __builtin_amdgcn_global_load_lds(AS1(g), AS3(d), 16, 0, 0);
    g += 8 * kstride;
    d += 2048;
  }
}

__device__ __forceinline__ void compute64(const ushort* As, const ushort* Bs,
                                          int w, int lane, floatx4 acc[4]) {
  const int fm = lane & 15;
  const int q  = lane >> 4;
  const int swz = fm & 7;
  const int arow = (w * 16 + fm) * 256;
  #pragma unroll
  for (int kt = 0; kt < 8; ++kt) {
    const int blk = ((kt * 4 + q) ^ swz) * 8;
    short8 af = *(const short8*)&As[arow + blk];
    #pragma unroll
    for (int nt = 0; nt < 4; ++nt) {
      short8 bfr = *(const short8*)&Bs[(nt * 16 + fm) * 256 + blk];
      acc[nt] = __builtin_amdgcn_mfma_f32_16x16x32_bf16(af, bfr, acc[nt], 0, 0, 0);
    }
  }
}

// ---------------------------------------------------------------------------
// prep: blocks 0..195 LN1+transpose (16 px each); blocks 196..963 qkv-w cvt.
// ---------------------------------------------------------------------------
__global__ __launch_bounds__(256) void prep_kernel(
    const float* __restrict__ x, const float* __restrict__ n1w,
    const float* __restrict__ n1b, const float* __restrict__ qkvw,
    ushort* __restrict__ t1, ushort* __restrict__ wcat)
{
  const int tid = threadIdx.x;
  const int bid = blockIdx.x;
  if (bid >= 196) {
    int idx = (bid - 196) * 256 + tid;       // < 196608
    wcat[idx] = f2bf(qkvw[idx]);
    return;
  }
  __shared__ float tile[256 * 17];
  __shared__ float red[2][16][16];
  __shared__ float mu[16], rsv[16];
  const int n0 = bid * 16;
  const int px = tid & 15, grp = tid >> 4;
  #pragma unroll 4
  for (int it = 0; it < 16; ++it) {
    int c = it * 16 + grp;
    tile[c * 17 + px] = x[(size_t)c * 3136 + n0 + px];
  }
  __syncthreads();
  float s = 0.f, ss = 0.f;
  #pragma unroll
  for (int i = 0; i < 16; ++i) {
    float v = tile[(grp * 16 + i) * 17 + px];
    s += v; ss += v * v;
  }
  red[0][px][grp] = s; red[1][px][grp] = ss;
  __syncthreads();
  if (tid < 16) {
    float s2 = 0.f, ss2 = 0.f;
    #pragma unroll
    for (int g = 0; g < 16; ++g) { s2 += red[0][tid][g]; ss2 += red[1][tid][g]; }
    float m = s2 * (1.f / 256.f);
    float var = ss2 * (1.f / 256.f) - m * m;
    mu[tid] = m;
    rsv[tid] = rsqrtf(var + 1e-5f);
  }
  __syncthreads();
  const float wc = n1w[tid], bc = n1b[tid];
  #pragma unroll 4
  for (int p = 0; p < 16; ++p) {
    float v = tile[tid * 17 + p];
    t1[(size_t)(n0 + p) * 256 + tid] = f2bf((v - mu[p]) * rsv[p] * wc + bc);
  }
}

// ---------------------------------------------------------------------------
// qkv: grid (12, 241). y<49: GEMM [3136,256]@[768,256]^T + bias (q scaled).
// y>=49: cvt blocks for pw|f1|f2 (589824 elems), consumed by attnmlp.
// ---------------------------------------------------------------------------
__global__ __launch_bounds__(256, 2) void qkv_kernel(
    const ushort* __restrict__ A, const ushort* __restrict__ B,
    const float* __restrict__ bias, ushort* __restrict__ out,
    const float* __restrict__ projw, const float* __restrict__ f1w,
    const float* __restrict__ f2w, ushort* __restrict__ wcat)
{
  const int tid = threadIdx.x;
  if (blockIdx.y >= 49) {
    int c = (blockIdx.y - 49) * 12 + blockIdx.x;     // 0..2303
    int idx = c * 256 + tid;                         // < 589824
    float v;
    if (idx < 65536)        v = projw[idx];
    else if (idx < 327680)  v = f1w[idx - 65536];
    else                    v = f2w[idx - 327680];
    wcat[196608 + idx] = f2bf(v);
    return;
  }
  __shared__ ushort As[16384], Bs[16384];
  const int lane = tid & 63, w = tid >> 6;
  const int m0 = blockIdx.y * 64, n0 = blockIdx.x * 64;
  floatx4 acc[4] = {{0.f,0.f,0.f,0.f},{0.f,0.f,0.f,0.f},
                    {0.f,0.f,0.f,0.f},{0.f,0.f,0.f,0.f}};
  stage64(A + (size_t)m0 * 256, 256, As, tid);
  stage64(B + (size_t)n0 * 256, 256, Bs, tid);
  asm volatile("s_waitcnt vmcnt(0)" ::: "memory");
  __syncthreads();
  compute64(As, Bs, w, lane, acc);
  const int fm = lane & 15, q4 = (lane >> 4) * 4;
  #pragma unroll
  for (int nt = 0; nt < 4; ++nt)
    #pragma unroll
    for (int r = 0; r < 4; ++r) {
      int m = m0 + w * 16 + q4 + r;
      int n = n0 + nt * 16 + fm;
      float v = acc[nt][r] + bias[n];
      if (n < 256) v *= 0.17677669529663687f;   // 1/sqrt(32) on q
      out[(size_t)m * 768 + n] = f2bf(v);
    }
}

// ---------------------------------------------------------------------------
// attnmlp: 4x4 query tile per block (grid 196), 512 threads.
// LDS (byte offsets; regions reused across phases):
//  Kh@0 (52000) | Vh@52000 (51200)  [attn phase]
//  proj ring-3 depth-2 @0: per-wave 3x2KB at wv*6144B (48KB, Kh-ONLY --
//    safe to stage before PV; Vh untouched)
//  fc ring-6 depth-5 @0: per-wave 6x2KB at wv*12288B (96KB, Kh+Vh -- staged
//    only AFTER the x1s barrier, when Vh is dead and all proj reads done)
//  pr@103200 f32 s67 (34304) -> x1s@103200 f32[16][264] -> hbuf@103200 (32768)
//  aas@137504 [16][264] -> t2s@137504 [16][256]
//  pstat@145952 | stats@146976
// ---------------------------------------------------------------------------
#define AM_SMEM 147104

__global__ __launch_bounds__(512, 1) void attnmlp_kernel(
    const ushort* __restrict__ qkv, const ushort* __restrict__ pw_bf,
    const float* __restrict__ projb, const float* __restrict__ x,
    const ushort* __restrict__ f1_bf, const float* __restrict__ f1b,
    const ushort* __restrict__ f2_bf, const float* __restrict__ f2b,
    const float* __restrict__ n2w, const float* __restrict__ n2b,
    float* __restrict__ outf)
{
  __shared__ __align__(16) char smem[AM_SMEM];
  ushort* Kh    = (ushort*)smem;
  ushort* Vh    = (ushort*)(smem + 52000);
  ushort* rings = (ushort*)smem;                 // slab regions (see header)
  float*  pr    = (float*)(smem + 103200);       // [16*8][67]
  float*  x1s   = (float*)(smem + 103200);       // [16][264] f32 (pr dead)
  ushort* hbuf  = (ushort*)(smem + 103200);      // [16][1024] (x1s dead)
  ushort* aas   = (ushort*)(smem + 137504);      // [16][264]
  ushort* t2s   = (ushort*)(smem + 137504);      // [16][256] (aas dead)
  float*  pstat = (float*)(smem + 145952);       // [8][16][2]
  float*  stats = (float*)(smem + 146976);       // [16][2]

  const int tid = threadIdx.x;
  const int wv = tid >> 6, lane = tid & 63;
  const int fm = lane & 15, q = lane >> 4;
  const int l4 = lane >> 2, lb = lane & 3;
  const int i0 = (blockIdx.x / 14) * 4, j0 = (blockIdx.x % 14) * 4;

  // proj ring-3 (Kh-only): per-wave 3 slabs of 1024 ushorts at wv*3072
  ushort* prb[3];
  #pragma unroll
  for (int i = 0; i < 3; ++i) prb[i] = rings + wv * 3072 + i * 1024;
  // fc ring-6: per-wave 6 slabs of 1024 ushorts at wv*6144 (spans Kh+Vh)
  ushort* rb[6];
  #pragma unroll
  for (int i = 0; i < 6; ++i) rb[i] = rings + wv * 6144 + i * 1024;

  // ---- halo load (zero-fill out-of-image) ----
  for (int s = tid; s < 3200; s += 512) {
    int p = s >> 5, ck = s & 31;
    int ii = i0 - 3 + p / 10, jj = j0 - 3 + p % 10;
    if (ii >= 0 && ii < 56 && jj >= 0 && jj < 56) {
      const ushort* kr = qkv + (size_t)(ii * 56 + jj) * 768 + 256 + ck * 8;
      short8 kv = *(const short8*)kr;
      u64 lo = ((const u64*)&kv)[0], hi = ((const u64*)&kv)[1];
      *(u64*)&Kh[p * 260 + ck * 8] = lo;
      *(u64*)&Kh[p * 260 + ck * 8 + 4] = hi;
      *(short8*)&Vh[p * 256 + ck * 8] = *(const short8*)(kr + 256);
    } else {
      *(u64*)&Kh[p * 260 + ck * 8] = 0ull;
      *(u64*)&Kh[p * 260 + ck * 8 + 4] = 0ull;
      short8 z = {0, 0, 0, 0, 0, 0, 0, 0};
      *(short8*)&Vh[p * 256 + ck * 8] = z;
    }
  }
  __syncthreads();

  // ---- scores + softmax: wave wv owns queries 2wv, 2wv+1 ----
  {
    const int h = lane >> 3, mg = lane & 7;
    #pragma unroll
    for (int qq = 0; qq < 2; ++qq) {
      const int p = wv * 2 + qq;
      const int qi = p >> 2, qj = p & 3;
      const int iq = i0 + qi, jq = j0 + qj;
      const ushort* qp = qkv + (size_t)(iq * 56 + jq) * 768 + h * 32;
      float qf[32];
      #pragma unroll
      for (int u = 0; u < 4; ++u) {
        short8 qv = *(const short8*)(qp + u * 8);
        #pragma unroll
        for (int e = 0; e < 8; ++e) qf[u * 8 + e] = bf2f((ushort)qv[e]);
      }
      float sv[7];
      float mx = -1e30f;
      #pragma unroll
      for (int k = 0; k < 7; ++k) {
        int m = mg + 8 * k;
        float s = -1e30f;
        if (m < 49) {
          int mi = m / 7, mj = m % 7;
          int ii = iq + mi - 3, jj = jq + mj - 3;
          if (ii >= 0 && ii < 56 && jj >= 0 && jj < 56) {
            int hrow = (qi + mi) * 10 + (qj + mj);
            const u64* k8 = (const u64*)&Kh[hrow * 260 + h * 32];
            float a = 0.f;
            #pragma unroll
            for (int u = 0; u < 8; ++u) {
              u64 kv = k8[u];
              #pragma unroll
              for (int e = 0; e < 4; ++e)
                a += qf[u * 4 + e] * bf2f((ushort)(kv >> (16 * e)));
            }
            s = a;
          }
        }
        sv[k] = s;
        mx = fmaxf(mx, s);
      }
      mx = fmaxf(mx, __shfl_xor(mx, 1));
      mx = fmaxf(mx, __shfl_xor(mx, 2));
      mx = fmaxf(mx, __shfl_xor(mx, 4));
      float sm = 0.f;
      #pragma unroll
      for (int k = 0; k < 7; ++k) { sv[k] = __expf(sv[k] - mx); sm += sv[k]; }
      sm += __shfl_xor(sm, 1);
      sm += __shfl_xor(sm, 2);
      sm += __shfl_xor(sm, 4);
      float inv = 1.f / sm;
      #pragma unroll
      for (int k = 0; k < 7; ++k) {
        int m = mg + 8 * k;
        pr[(p * 8 + h) * 67 + m] = sv[k] * inv;
      }
    }
  }
  __syncthreads();     // Kh dead; pr visible

#define STAGE_P(kt, buf) do { \
    _Pragma("unroll") \
    for (int i_ = 0; i_ < 2; ++i_) { \
      int row_ = i_ * 16 + l4; \
      const ushort* g_ = pw_bf + (size_t)(wv * 32 + row_) * 256 + (kt) * 32 + (lb ^ (row_ & 3)) * 8; \
      __builtin_amdgcn_global_load_lds(AS1(g_), AS3((buf) + i_ * 512 + lane * 8), 16, 0, 0); \
    } } while (0)
  // proj prologue: 2 stages in flight, Kh-only region (Vh still live for PV)
  STAGE_P(0, prb[0]);
  STAGE_P(1, prb[1]);

  // ---- PV: thread = (query p = tid>>5, 8-ch group cg), single pass ----
  {
    const int p = tid >> 5, cg = tid & 31, hh = cg >> 2;
    const int qi = p >> 2, qj = p & 3;
    float acc8[8] = {0, 0, 0, 0, 0, 0, 0, 0};
    #pragma unroll
    for (int mi = 0; mi < 7; ++mi)
      #pragma unroll
      for (int mj = 0; mj < 7; ++mj) {
        int m = mi * 7 + mj;
        int hrow = (qi + mi) * 10 + (qj + mj);
        float pm = pr[(p * 8 + hh) * 67 + m];
        short8 v8 = *(const short8*)&Vh[hrow * 256 + cg * 8];
        #pragma unroll
        for (int e = 0; e < 8; ++e)
          acc8[e] += pm * bf2f((ushort)v8[e]);
      }
    short8 o;
    #pragma unroll
    for (int e = 0; e < 8; ++e) o[e] = (short)f2bf(acc8[e]);
    *(short8*)&aas[p * 264 + cg * 8] = o;
  }
  __syncthreads();     // aas visible; pr/Vh dead; proj stages 0,1 landed

  // ---- proj: wave wv -> out ch wv*32..+31, all 16 px; resid from x ----
  // ring-3 depth-2: at iter kt, in-flight = stages kt+1,kt+2 (distinct bufs)
  {
    floatx4 pacc[2] = {{0.f,0.f,0.f,0.f},{0.f,0.f,0.f,0.f}};
    #pragma unroll
    for (int kt = 0; kt < 8; ++kt) {
      if (kt < 6) {
        STAGE_P(kt + 2, prb[(kt + 2) % 3]);
        asm volatile("s_waitcnt vmcnt(4)" ::: "memory");   // stage kt landed
      } else if (kt == 6) {
        asm volatile("s_waitcnt vmcnt(0)" ::: "memory");
      }
      ushort* cur = prb[kt % 3];
      short8 af = *(const short8*)&aas[fm * 264 + kt * 32 + q * 8];
      #pragma unroll
      for (int nt = 0; nt < 2; ++nt) {
        int r = nt * 16 + fm;
        short8 bfr = *(const short8*)&cur[r * 32 + (q ^ (r & 3)) * 8];
        pacc[nt] = __builtin_amdgcn_mfma_f32_16x16x32_bf16(af, bfr, pacc[nt], 0, 0, 0);
      }
    }
    #pragma unroll
    for (int nt = 0; nt < 2; ++nt) {
      int ch = wv * 32 + nt * 16 + fm;
      floatx4 rx = *(const floatx4*)(x + (size_t)ch * 3136 + (i0 + q) * 56 + j0);
      #pragma unroll
      for (int r = 0; r < 4; ++r) {
        int px = q * 4 + r;
        x1s[px * 264 + ch] = pacc[nt][r] + projb[ch] + rx[r];
      }
    }
  }
  __syncthreads();     // x1s visible; ALL waves' proj slab reads done; Vh dead

#define STAGE_F1(c, kt, buf) do { \
    _Pragma("unroll") \
    for (int i_ = 0; i_ < 2; ++i_) { \
      int row_ = i_ * 16 + l4; \
      const ushort* g_ = f1_bf + (size_t)((c) * 32 + row_) * 256 + (kt) * 32 + (lb ^ (row_ & 3)) * 8; \
      __builtin_amdgcn_global_load_lds(AS1(g_), AS3((buf) + i_ * 512 + lane * 8), 16, 0, 0); \
    } } while (0)
  // fc1 prologue (safe now: post-barrier). Lands across the LN2 phase.
  #pragma unroll
  for (int s = 0; s < 5; ++s) STAGE_F1(wv, s, rb[s]);

  // ---- LN2 from x1s; residual kept in regs (matches fc2 acc layout) ----
  floatx4 xv[2];
  xv[0] = *(const floatx4*)&x1s[fm * 264 + wv * 32 + q * 4];
  xv[1] = *(const floatx4*)&x1s[fm * 264 + wv * 32 + 16 + q * 4];
  {
    float s = 0.f, ss = 0.f;
    #pragma unroll
    for (int nt = 0; nt < 2; ++nt)
      #pragma unroll
      for (int e = 0; e < 4; ++e) { s += xv[nt][e]; ss += xv[nt][e] * xv[nt][e]; }
    s += __shfl_xor(s, 16); ss += __shfl_xor(ss, 16);
    s += __shfl_xor(s, 32); ss += __shfl_xor(ss, 32);
    if (lane < 16) { pstat[(wv * 16 + lane) * 2] = s; pstat[(wv * 16 + lane) * 2 + 1] = ss; }
  }
  __syncthreads();
  if (tid < 16) {
    float s2 = 0.f, ss2 = 0.f;
    #pragma unroll
    for (int ww = 0; ww < 8; ++ww) {
      s2 += pstat[(ww * 16 + tid) * 2];
      ss2 += pstat[(ww * 16 + tid) * 2 + 1];
    }
    float mu = s2 * (1.f / 256.f);
    float var = ss2 * (1.f / 256.f) - mu * mu;
    stats[tid * 2] = mu;
    stats[tid * 2 + 1] = rsqrtf(var + 1e-5f);
  }
  __syncthreads();
  {
    float mu = stats[fm * 2], rs = stats[fm * 2 + 1];
    #pragma unroll
    for (int nt = 0; nt < 2; ++nt) {
      int ch0 = wv * 32 + nt * 16 + q * 4;
      ushort4v o;
      #pragma unroll
      for (int e = 0; e < 4; ++e)
        o[e] = f2bf((xv[nt][e] - mu) * rs * n2w[ch0 + e] + n2b[ch0 + e]);
      int slot = ch0 >> 3;
      *(ushort4v*)&t2s[fm * 256 + ((slot ^ (fm & 7)) * 8) + (ch0 & 7)] = o;
    }
  }
  // fc1 bias for this wave's 32-col chunks {wv, wv+8, wv+16, wv+24}
  float f1br[4][2];
  #pragma unroll
  for (int ci = 0; ci < 4; ++ci)
    #pragma unroll
    for (int nt = 0; nt < 2; ++nt)
      f1br[ci][nt] = f1b[(wv + ci * 8) * 32 + nt * 16 + fm];
  __syncthreads();     // t2s complete

  // ---- fc1: wave wv -> 4 chunks of 32 h-cols; gelu -> hbuf; ring-6 ----
  {
    floatx4 fa[2] = {{0.f,0.f,0.f,0.f},{0.f,0.f,0.f,0.f}};
    for (int sidx = 0; sidx < 32; ++sidx) {
      if (sidx < 27) {
        int s5 = sidx + 5;
        STAGE_F1((s5 >> 3) * 8 + wv, s5 & 7, rb[s5 % 6]);
        asm volatile("s_waitcnt vmcnt(10)" ::: "memory");  // stage sidx landed
      } else if (sidx == 27) {
        asm volatile("s_waitcnt vmcnt(0)" ::: "memory");
      }
      const int kt = sidx & 7;
      ushort* cur = rb[sidx % 6];
      short8 af = *(const short8*)&t2s[fm * 256 + (((kt * 4 + q) ^ (fm & 7)) * 8)];
      #pragma unroll
      for (int nt = 0; nt < 2; ++nt) {
        int r = nt * 16 + fm;
        short8 bfr = *(const short8*)&cur[r * 32 + (q ^ (r & 3)) * 8];
        fa[nt] = __builtin_amdgcn_mfma_f32_16x16x32_bf16(af, bfr, fa[nt], 0, 0, 0);
      }
      if (kt == 7) {
        const int ci = sidx >> 3;
        #pragma unroll
        for (int nt = 0; nt < 2; ++nt) {
          int hc = (wv + ci * 8) * 32 + nt * 16 + fm;
          #pragma unroll
          for (int r4 = 0; r4 < 4; ++r4) {
            int prow = q * 4 + r4;
            float v = fa[nt][r4] + f1br[ci][nt];
            v = 0.5f * v * (1.0f + erff(v * 0.70710678118654752f));
            hbuf[prow * 1024 + (((hc >> 3) ^ (prow & 7)) * 8) + (hc & 7)] = f2bf(v);
            fa[nt][r4] = 0.f;
          }
        }
      }
    }
  }
#define STAGE_F2(kt, buf) do { \
    _Pragma("unroll") \
    for (int i_ = 0; i_ < 2; ++i_) { \
      int row_ = i_ * 16 + l4; \
      const ushort* g_ = f2_bf + (size_t)(wv * 32 + row_) * 1024 + (kt) * 32 + (lb ^ (row_ & 3)) * 8; \
      __builtin_amdgcn_global_load_lds(AS1(g_), AS3((buf) + i_ * 512 + lane * 8), 16, 0, 0); \
    } } while (0)
  // fc2 prologue into own ring (own fc1 reads done in program order)
  #pragma unroll
  for (int s = 0; s < 5; ++s) STAGE_F2(s, rb[s]);
  __syncthreads();     // hbuf complete

  // ---- fc2: wave wv -> out channels wv*32..+31; residual from regs ----
  {
    floatx4 ga[2] = {{0.f,0.f,0.f,0.f},{0.f,0.f,0.f,0.f}};
    for (int kt = 0; kt < 32; ++kt) {
      if (kt < 27) {
        STAGE_F2(kt + 5, rb[(kt + 5) % 6]);
        asm volatile("s_waitcnt vmcnt(10)" ::: "memory");  // stage kt landed
      } else if (kt == 27) {
        asm volatile("s_waitcnt vmcnt(0)" ::: "memory");
      }
      ushort* cur = rb[kt % 6];
      short8 bfr = *(const short8*)&hbuf[fm * 1024 + (((kt * 4 + q) ^ (fm & 7)) * 8)];
      #pragma unroll
      for (int mt = 0; mt < 2; ++mt) {
        int r = mt * 16 + fm;
        short8 af = *(const short8*)&cur[r * 32 + (q ^ (r & 3)) * 8];
        ga[mt] = __builtin_amdgcn_mfma_f32_16x16x32_bf16(af, bfr, ga[mt], 0, 0, 0);
      }
    }
    #pragma unroll
    for (int mt = 0; mt < 2; ++mt) {
      #pragma unroll
      for (int r4 = 0; r4 < 4; ++r4) {
        int ch = wv * 32 + mt * 16 + q * 4 + r4;
        int n = (i0 + (fm >> 2)) * 56 + j0 + (fm & 3);
        outf[(size_t)ch * 3136 + n] = ga[mt][r4] + f2b[ch] + xv[mt][r4];
      }
    }
  }
#undef STAGE_P
#undef STAGE_F1
#undef STAGE_F2
}

// ---------------------------------------------------------------------------
extern "C" void kernel_launch(void* const* d_in, const int* in_sizes, int n_in,
                              void* d_out, int out_size, void* d_ws, size_t ws_size,
                              hipStream_t stream) {
  const float* x     = (const float*)d_in[0];
  const float* n1w   = (const float*)d_in[1];
  const float* n1b   = (const float*)d_in[2];
  const float* qkvw  = (const float*)d_in[3];
  const float* qkvb  = (const float*)d_in[4];
  const float* projw = (const float*)d_in[5];
  const float* projb = (const float*)d_in[6];
  const float* n2w   = (const float*)d_in[7];
  const float* n2b   = (const float*)d_in[8];
  const float* f1w   = (const float*)d_in[9];
  const float* f1b   = (const float*)d_in[10];
  const float* f2w   = (const float*)d_in[11];
  const float* f2b   = (const float*)d_in[12];

  char* ws = (char*)d_ws;
  ushort* wcat = (ushort*)(ws + 0);            // 786432 bf16
  ushort* t    = (ushort*)(ws + 4784128);      // 802816 bf16 (t1)
  ushort* qh   = (ushort*)(ws + 6389760);      // qkv [3136][768]

  const ushort* qw_bf = wcat;
  const ushort* pw_bf = wcat + 196608;
  const ushort* f1_bf = wcat + 262144;
  const ushort* f2_bf = wcat + 524288;
  float* outf = (float*)d_out;

  hipLaunchKernelGGL(prep_kernel, dim3(964), dim3(256), 0, stream,
                     x, n1w, n1b, qkvw, t, wcat);
  hipLaunchKernelGGL(qkv_kernel, dim3(12, 241), dim3(256), 0, stream,
                     t, qw_bf, qkvb, qh, projw, f1w, f2w, wcat);
  hipLaunchKernelGGL(attnmlp_kernel, dim3(196), dim3(512), 0, stream,
                     qh, pw_bf, projb, x, f1_bf, f1b, f2_bf, f2b,
                     n2w, n2b, outf);
}

// Round 14
// 125.520 us; speedup vs baseline: 1.0672x; 1.0672x over previous
//
#include <hip/hip_runtime.h>
#include <math.h>

// ---------------------------------------------------------------------------
// LocalTransformerBlock2d: B=1, C=256, H=W=56 (N=3136), 8 heads x d=32,
// 7x7 local window. fp32 in/out; bf16 MFMA GEMMs.
// 3 stream-ordered kernels:
//   prep(qw cvt + LN1T) -> qkv(+pw/f1/f2 cvt blocks) -> attnmlp
// R13 regressed (attnmlp 40.5->48us): fc1 rechunk halved per-wait MFMA work.
// R14 = R9 (best verified, 125.9us) + ONE change: fc2 dbuf-2 -> ring-3
// depth-2 (3x2KB in the wave's own fslab region; vmcnt(4), tail vmcnt(0)).
// ---------------------------------------------------------------------------

typedef unsigned int uint;
typedef unsigned short ushort;
typedef unsigned long long u64;
typedef __attribute__((ext_vector_type(8))) short short8;   // 8 bf16
typedef __attribute__((ext_vector_type(4))) float floatx4;  // MFMA acc
typedef __attribute__((ext_vector_type(4))) unsigned short ushort4v;

#define AS1(p) (const __attribute__((address_space(1))) void*)(p)
#define AS3(p) (__attribute__((address_space(3))) void*)(p)

__device__ __forceinline__ float bf2f(ushort u) {
  union { uint i; float f; } v; v.i = ((uint)u) << 16; return v.f;
}
__device__ __forceinline__ ushort f2bf(float f) {
  union { float f; uint i; } v; v.f = f;
  uint u = v.i;
  return (ushort)((u + 0x7fffu + ((u >> 16) & 1u)) >> 16);
}

// Stage a 64-row x 256-col bf16 panel into LDS with XOR swizzle.
__device__ __forceinline__ void stage64(const ushort* src, int kstride,
                                        ushort* dstBase, int tid) {
  const int srow = tid >> 5;
  const int scb  = (tid & 31) ^ srow;
  const ushort* g = src + (size_t)srow * kstride + scb * 8;
  ushort* d = dstBase + tid * 8;
  #pragma unroll
  for (int r = 0; r < 8; ++r) {
    __builtin_amdgcn_global_load_lds(AS1(g), AS3(d), 16, 0, 0);
    g += 8 * kstride;
    d += 2048;
  }
}

__device__ __forceinline__ void compute64(const ushort* As, const ushort* Bs,
                                          int w, int lane, floatx4 acc[4]) {
  const int fm = lane & 15;
  const int q  = lane >> 4;
  const int swz = fm & 7;
  const int arow = (w * 16 + fm) * 256;
  #pragma unroll
  for (int kt = 0; kt < 8; ++kt) {
    const int blk = ((kt * 4 + q) ^ swz) * 8;
    short8 af = *(const short8*)&As[arow + blk];
    #pragma unroll
    for (int nt = 0; nt < 4; ++nt) {
      short8 bfr = *(const short8*)&Bs[(nt * 16 + fm) * 256 + blk];
      acc[nt] = __builtin_amdgcn_mfma_f32_16x16x32_bf16(af, bfr, acc[nt], 0, 0, 0);
    }
  }
}

// ---------------------------------------------------------------------------
// prep: blocks 0..195 LN1+transpose (16 px each); blocks 196..963 qkv-w cvt.
// ---------------------------------------------------------------------------
__global__ __launch_bounds__(256) void prep_kernel(
    const float* __restrict__ x, const float* __restrict__ n1w,
    const float* __restrict__ n1b, const float* __restrict__ qkvw,
    ushort* __restrict__ t1, ushort* __restrict__ wcat)
{
  const int tid = threadIdx.x;
  const int bid = blockIdx.x;
  if (bid >= 196) {
    int idx = (bid - 196) * 256 + tid;       // < 196608
    wcat[idx] = f2bf(qkvw[idx]);
    return;
  }
  __shared__ float tile[256 * 17];
  __shared__ float red[2][16][16];
  __shared__ float mu[16], rsv[16];
  const int n0 = bid * 16;
  const int px = tid & 15, grp = tid >> 4;
  #pragma unroll 4
  for (int it = 0; it < 16; ++it) {
    int c = it * 16 + grp;
    tile[c * 17 + px] = x[(size_t)c * 3136 + n0 + px];
  }
  __syncthreads();
  float s = 0.f, ss = 0.f;
  #pragma unroll
  for (int i = 0; i < 16; ++i) {
    float v = tile[(grp * 16 + i) * 17 + px];
    s += v; ss += v * v;
  }
  red[0][px][grp] = s; red[1][px][grp] = ss;
  __syncthreads();
  if (tid < 16) {
    float s2 = 0.f, ss2 = 0.f;
    #pragma unroll
    for (int g = 0; g < 16; ++g) { s2 += red[0][tid][g]; ss2 += red[1][tid][g]; }
    float m = s2 * (1.f / 256.f);
    float var = ss2 * (1.f / 256.f) - m * m;
    mu[tid] = m;
    rsv[tid] = rsqrtf(var + 1e-5f);
  }
  __syncthreads();
  const float wc = n1w[tid], bc = n1b[tid];
  #pragma unroll 4
  for (int p = 0; p < 16; ++p) {
    float v = tile[tid * 17 + p];
    t1[(size_t)(n0 + p) * 256 + tid] = f2bf((v - mu[p]) * rsv[p] * wc + bc);
  }
}

// ---------------------------------------------------------------------------
// qkv: grid (12, 241). y<49: GEMM [3136,256]@[768,256]^T + bias (q scaled).
// y>=49: cvt blocks for pw|f1|f2 (589824 elems), consumed by attnmlp.
// ---------------------------------------------------------------------------
__global__ __launch_bounds__(256, 2) void qkv_kernel(
    const ushort* __restrict__ A, const ushort* __restrict__ B,
    const float* __restrict__ bias, ushort* __restrict__ out,
    const float* __restrict__ projw, const float* __restrict__ f1w,
    const float* __restrict__ f2w, ushort* __restrict__ wcat)
{
  const int tid = threadIdx.x;
  if (blockIdx.y >= 49) {
    int c = (blockIdx.y - 49) * 12 + blockIdx.x;     // 0..2303
    int idx = c * 256 + tid;                         // < 589824
    float v;
    if (idx < 65536)        v = projw[idx];
    else if (idx < 327680)  v = f1w[idx - 65536];
    else                    v = f2w[idx - 327680];
    wcat[196608 + idx] = f2bf(v);
    return;
  }
  __shared__ ushort As[16384], Bs[16384];
  const int lane = tid & 63, w = tid >> 6;
  const int m0 = blockIdx.y * 64, n0 = blockIdx.x * 64;
  floatx4 acc[4] = {{0.f,0.f,0.f,0.f},{0.f,0.f,0.f,0.f},
                    {0.f,0.f,0.f,0.f},{0.f,0.f,0.f,0.f}};
  stage64(A + (size_t)m0 * 256, 256, As, tid);
  stage64(B + (size_t)n0 * 256, 256, Bs, tid);
  asm volatile("s_waitcnt vmcnt(0)" ::: "memory");
  __syncthreads();
  compute64(As, Bs, w, lane, acc);
  const int fm = lane & 15, q4 = (lane >> 4) * 4;
  #pragma unroll
  for (int nt = 0; nt < 4; ++nt)
    #pragma unroll
    for (int r = 0; r < 4; ++r) {
      int m = m0 + w * 16 + q4 + r;
      int n = n0 + nt * 16 + fm;
      float v = acc[nt][r] + bias[n];
      if (n < 256) v *= 0.17677669529663687f;   // 1/sqrt(32) on q
      out[(size_t)m * 768 + n] = f2bf(v);
    }
}

// ---------------------------------------------------------------------------
// attnmlp: 4x4 query tile per block (grid 196), 512 threads (2 waves/SIMD).
// LDS (byte offsets; R9 layout, verified at 125.9us):
//  attn: Kh@0 (52000) | Vh@52000 (51200) | pr@103200 f32 stride67 (34304)
//        aas@137504 (8448)
//  proj: pslab@0 (Kh dead, 8x4KB) | x1s@103200 f32[16][264] (pr dead)
//  mlp : hbuf@0 (32768, pslab dead) | fslab@32768 (8x8KB) | t2s@120096
//        pstat@128288 | stats@129312
// ---------------------------------------------------------------------------
#define AM_SMEM 145952

__global__ __launch_bounds__(512, 1) void attnmlp_kernel(
    const ushort* __restrict__ qkv, const ushort* __restrict__ pw_bf,
    const float* __restrict__ projb, const float* __restrict__ x,
    const ushort* __restrict__ f1_bf, const float* __restrict__ f1b,
    const ushort* __restrict__ f2_bf, const float* __restrict__ f2b,
    const float* __restrict__ n2w, const float* __restrict__ n2b,
    float* __restrict__ outf)
{
  __shared__ __align__(16) char smem[AM_SMEM];
  ushort* Kh    = (ushort*)smem;
  ushort* Vh    = (ushort*)(smem + 52000);
  float*  pr    = (float*)(smem + 103200);       // [16*8][67]
  ushort* aas   = (ushort*)(smem + 137504);      // [16][264]
  ushort* pslab = (ushort*)smem;                 // proj slabs (Kh dead)
  float*  x1s   = (float*)(smem + 103200);       // [16][264] f32 (pr dead)
  ushort* hbuf  = (ushort*)smem;                 // [16][1024] (pslab dead)
  ushort* fslab = (ushort*)(smem + 32768);       // 8 x 4096 elems
  ushort* t2s   = (ushort*)(smem + 120096);      // [16][256]
  float*  pstat = (float*)(smem + 128288);       // [8][16][2]
  float*  stats = (float*)(smem + 129312);       // [16][2]

  const int tid = threadIdx.x;
  const int wv = tid >> 6, lane = tid & 63;
  const int fm = lane & 15, q = lane >> 4;
  const int l4 = lane >> 2, lb = lane & 3;
  const int i0 = (blockIdx.x / 14) * 4, j0 = (blockIdx.x % 14) * 4;

  // ---- halo load (zero-fill out-of-image) ----
  for (int s = tid; s < 3200; s += 512) {
    int p = s >> 5, ck = s & 31;
    int ii = i0 - 3 + p / 10, jj = j0 - 3 + p % 10;
    if (ii >= 0 && ii < 56 && jj >= 0 && jj < 56) {
      const ushort* kr = qkv + (size_t)(ii * 56 + jj) * 768 + 256 + ck * 8;
      short8 kv = *(const short8*)kr;
      u64 lo = ((const u64*)&kv)[0], hi = ((const u64*)&kv)[1];
      *(u64*)&Kh[p * 260 + ck * 8] = lo;
      *(u64*)&Kh[p * 260 + ck * 8 + 4] = hi;
      *(short8*)&Vh[p * 256 + ck * 8] = *(const short8*)(kr + 256);
    } else {
      *(u64*)&Kh[p * 260 + ck * 8] = 0ull;
      *(u64*)&Kh[p * 260 + ck * 8 + 4] = 0ull;
      short8 z = {0, 0, 0, 0, 0, 0, 0, 0};
      *(short8*)&Vh[p * 256 + ck * 8] = z;
    }
  }
  __syncthreads();

  // ---- scores + softmax: wave wv owns queries 2wv, 2wv+1 ----
  {
    const int h = lane >> 3, mg = lane & 7;
    #pragma unroll
    for (int qq = 0; qq < 2; ++qq) {
      const int p = wv * 2 + qq;
      const int qi = p >> 2, qj = p & 3;
      const int iq = i0 + qi, jq = j0 + qj;
      const ushort* qp = qkv + (size_t)(iq * 56 + jq) * 768 + h * 32;
      float qf[32];
      #pragma unroll
      for (int u = 0; u < 4; ++u) {
        short8 qv = *(const short8*)(qp + u * 8);
        #pragma unroll
        for (int e = 0; e < 8; ++e) qf[u * 8 + e] = bf2f((ushort)qv[e]);
      }
      float sv[7];
      float mx = -1e30f;
      #pragma unroll
      for (int k = 0; k < 7; ++k) {
        int m = mg + 8 * k;
        float s = -1e30f;
        if (m < 49) {
          int mi = m / 7, mj = m % 7;
          int ii = iq + mi - 3, jj = jq + mj - 3;
          if (ii >= 0 && ii < 56 && jj >= 0 && jj < 56) {
            int hrow = (qi + mi) * 10 + (qj + mj);
            const u64* k8 = (const u64*)&Kh[hrow * 260 + h * 32];
            float a = 0.f;
            #pragma unroll
            for (int u = 0; u < 8; ++u) {
              u64 kv = k8[u];
              #pragma unroll
              for (int e = 0; e < 4; ++e)
                a += qf[u * 4 + e] * bf2f((ushort)(kv >> (16 * e)));
            }
            s = a;
          }
        }
        sv[k] = s;
        mx = fmaxf(mx, s);
      }
      mx = fmaxf(mx, __shfl_xor(mx, 1));
      mx = fmaxf(mx, __shfl_xor(mx, 2));
      mx = fmaxf(mx, __shfl_xor(mx, 4));
      float sm = 0.f;
      #pragma unroll
      for (int k = 0; k < 7; ++k) { sv[k] = __expf(sv[k] - mx); sm += sv[k]; }
      sm += __shfl_xor(sm, 1);
      sm += __shfl_xor(sm, 2);
      sm += __shfl_xor(sm, 4);
      float inv = 1.f / sm;
      #pragma unroll
      for (int k = 0; k < 7; ++k) {
        int m = mg + 8 * k;
        pr[(p * 8 + h) * 67 + m] = sv[k] * inv;
      }
    }
  }
  __syncthreads();     // Kh dead; pr visible

  // per-wave proj slab dbuf in dead Kh region
  ushort* ps0 = pslab + wv * 2048;
  ushort* ps1 = ps0 + 1024;
#define STAGE_P(kt, buf) do { \
    _Pragma("unroll") \
    for (int i_ = 0; i_ < 2; ++i_) { \
      int row_ = i_ * 16 + l4; \
      const ushort* g_ = pw_bf + (size_t)(wv * 32 + row_) * 256 + (kt) * 32 + (lb ^ (row_ & 3)) * 8; \
      __builtin_amdgcn_global_load_lds(AS1(g_), AS3((buf) + i_ * 512 + lane * 8), 16, 0, 0); \
    } } while (0)
  STAGE_P(0, ps0);     // overlaps PV compute

  // ---- PV: thread = (query p = tid>>5, 8-ch group cg), single pass ----
  {
    const int p = tid >> 5, cg = tid & 31, hh = cg >> 2;
    const int qi = p >> 2, qj = p & 3;
    float acc8[8] = {0, 0, 0, 0, 0, 0, 0, 0};
    #pragma unroll
    for (int mi = 0; mi < 7; ++mi)
      #pragma unroll
      for (int mj = 0; mj < 7; ++mj) {
        int m = mi * 7 + mj;
        int hrow = (qi + mi) * 10 + (qj + mj);
        float pm = pr[(p * 8 + hh) * 67 + m];
        short8 v8 = *(const short8*)&Vh[hrow * 256 + cg * 8];
        #pragma unroll
        for (int e = 0; e < 8; ++e)
          acc8[e] += pm * bf2f((ushort)v8[e]);
      }
    short8 o;
    #pragma unroll
    for (int e = 0; e < 8; ++e) o[e] = (short)f2bf(acc8[e]);
    *(short8*)&aas[p * 264 + cg * 8] = o;
  }
  __syncthreads();     // aas visible; pr/Vh dead after this phase

  // ---- proj: wave wv -> out ch wv*32..+31, all 16 px; resid from x ----
  {
    floatx4 pacc[2] = {{0.f,0.f,0.f,0.f},{0.f,0.f,0.f,0.f}};
    for (int kt = 0; kt < 8; ++kt) {
      ushort* cur = (kt & 1) ? ps1 : ps0;
      ushort* nxt = (kt & 1) ? ps0 : ps1;
      if (kt < 7) {
        STAGE_P(kt + 1, nxt);
        asm volatile("s_waitcnt vmcnt(2)" ::: "memory");
      } else {
        asm volatile("s_waitcnt vmcnt(0)" ::: "memory");
      }
      short8 af = *(const short8*)&aas[fm * 264 + kt * 32 + q * 8];
      #pragma unroll
      for (int nt = 0; nt < 2; ++nt) {
        int r = nt * 16 + fm;
        short8 bfr = *(const short8*)&cur[r * 32 + (q ^ (r & 3)) * 8];
        pacc[nt] = __builtin_amdgcn_mfma_f32_16x16x32_bf16(af, bfr, pacc[nt], 0, 0, 0);
      }
    }
    #pragma unroll
    for (int nt = 0; nt < 2; ++nt) {
      int ch = wv * 32 + nt * 16 + fm;
      floatx4 rx = *(const floatx4*)(x + (size_t)ch * 3136 + (i0 + q) * 56 + j0);
      #pragma unroll
      for (int r = 0; r < 4; ++r) {
        int px = q * 4 + r;
        x1s[px * 264 + ch] = pacc[nt][r] + projb[ch] + rx[r];
      }
    }
  }
  // kick fc1 slab 0 (fslab region: dead Kh/Vh, own 8KB); lands across barrier
  ushort* fs0 = fslab + wv * 4096;
  ushort* fs1 = fs0 + 2048;
#define STAGE_F1(c, kt, buf) do { \
    _Pragma("unroll") \
    for (int i_ = 0; i_ < 4; ++i_) { \
      int row_ = i_ * 16 + l4; \
      const ushort* g_ = f1_bf + (size_t)((c) * 64 + row_) * 256 + (kt) * 32 + (lb ^ (row_ & 3)) * 8; \
      __builtin_amdgcn_global_load_lds(AS1(g_), AS3((buf) + i_ * 512 + lane * 8), 16, 0, 0); \
    } } while (0)
  STAGE_F1(wv, 0, fs0);
  __syncthreads();     // x1s complete

  // ---- LN2 from x1s; residual kept in regs (matches fc2 acc layout) ----
  floatx4 xv[2];
  xv[0] = *(const floatx4*)&x1s[fm * 264 + wv * 32 + q * 4];
  xv[1] = *(const floatx4*)&x1s[fm * 264 + wv * 32 + 16 + q * 4];
  {
    float s = 0.f, ss = 0.f;
    #pragma unroll
    for (int nt = 0; nt < 2; ++nt)
      #pragma unroll
      for (int e = 0; e < 4; ++e) { s += xv[nt][e]; ss += xv[nt][e] * xv[nt][e]; }
    s += __shfl_xor(s, 16); ss += __shfl_xor(ss, 16);
    s += __shfl_xor(s, 32); ss += __shfl_xor(ss, 32);
    if (lane < 16) { pstat[(wv * 16 + lane) * 2] = s; pstat[(wv * 16 + lane) * 2 + 1] = ss; }
  }
  __syncthreads();
  if (tid < 16) {
    float s2 = 0.f, ss2 = 0.f;
    #pragma unroll
    for (int ww = 0; ww < 8; ++ww) {
      s2 += pstat[(ww * 16 + tid) * 2];
      ss2 += pstat[(ww * 16 + tid) * 2 + 1];
    }
    float mu = s2 * (1.f / 256.f);
    float var = ss2 * (1.f / 256.f) - mu * mu;
    stats[tid * 2] = mu;
    stats[tid * 2 + 1] = rsqrtf(var + 1e-5f);
  }
  __syncthreads();
  {
    float mu = stats[fm * 2], rs = stats[fm * 2 + 1];
    #pragma unroll
    for (int nt = 0; nt < 2; ++nt) {
      int ch0 = wv * 32 + nt * 16 + q * 4;
      ushort4v o;
      #pragma unroll
      for (int e = 0; e < 4; ++e)
        o[e] = f2bf((xv[nt][e] - mu) * rs * n2w[ch0 + e] + n2b[ch0 + e]);
      int slot = ch0 >> 3;
      *(ushort4v*)&t2s[fm * 256 + ((slot ^ (fm & 7)) * 8) + (ch0 & 7)] = o;
    }
  }
  // preload fc1 bias for this wave's chunks {wv, wv+8}
  float f1br[2][4];
  #pragma unroll
  for (int ci = 0; ci < 2; ++ci)
    #pragma unroll
    for (int nt = 0; nt < 4; ++nt)
      f1br[ci][nt] = f1b[(wv + ci * 8) * 64 + nt * 16 + fm];
  __syncthreads();     // t2s complete

  // ---- fc1: wave wv -> h chunks {wv, wv+8} (64 cols each), gelu -> hbuf ----
  {
    floatx4 fa[4] = {{0.f,0.f,0.f,0.f},{0.f,0.f,0.f,0.f},
                     {0.f,0.f,0.f,0.f},{0.f,0.f,0.f,0.f}};
    for (int sidx = 0; sidx < 16; ++sidx) {
      const int kt = sidx & 7;
      const int ci = sidx >> 3;
      ushort* cur = (sidx & 1) ? fs1 : fs0;
      ushort* nxt = (sidx & 1) ? fs0 : fs1;
      if (sidx < 15) {
        int s1 = sidx + 1;
        STAGE_F1(wv + (s1 >> 3) * 8, s1 & 7, nxt);
        asm volatile("s_waitcnt vmcnt(4)" ::: "memory");
      } else {
        asm volatile("s_waitcnt vmcnt(0)" ::: "memory");
      }
      short8 af = *(const short8*)&t2s[fm * 256 + (((kt * 4 + q) ^ (fm & 7)) * 8)];
      #pragma unroll
      for (int nt = 0; nt < 4; ++nt) {
        int r = nt * 16 + fm;
        short8 bfr = *(const short8*)&cur[r * 32 + (q ^ (r & 3)) * 8];
        fa[nt] = __builtin_amdgcn_mfma_f32_16x16x32_bf16(af, bfr, fa[nt], 0, 0, 0);
      }
      if (kt == 7) {
        #pragma unroll
        for (int nt = 0; nt < 4; ++nt) {
          int hc = (wv + ci * 8) * 64 + nt * 16 + fm;
          #pragma unroll
          for (int r4 = 0; r4 < 4; ++r4) {
            int prow = q * 4 + r4;
            float v = fa[nt][r4] + f1br[ci][nt];
            v = 0.5f * v * (1.0f + erff(v * 0.70710678118654752f));
            hbuf[prow * 1024 + (((hc >> 3) ^ (prow & 7)) * 8) + (hc & 7)] = f2bf(v);
            fa[nt][r4] = 0.f;
          }
        }
      }
    }
  }
  // fc2 ring-3 of 2KB slabs inside the wave's own fslab region (R14 change)
  ushort* gs3[3] = {fs0, fs0 + 1024, fs0 + 2048};
#define STAGE_F2(kt, buf) do { \
    _Pragma("unroll") \
    for (int i_ = 0; i_ < 2; ++i_) { \
      int row_ = i_ * 16 + l4; \
      const ushort* g_ = f2_bf + (size_t)(wv * 32 + row_) * 1024 + (kt) * 32 + (lb ^ (row_ & 3)) * 8; \
      __builtin_amdgcn_global_load_lds(AS1(g_), AS3((buf) + i_ * 512 + lane * 8), 16, 0, 0); \
    } } while (0)
  STAGE_F2(0, gs3[0]);
  STAGE_F2(1, gs3[1]);
  __syncthreads();     // hbuf complete (also drains prologue stages)

  // ---- fc2: wave wv -> out channels wv*32..+31; residual from regs ----
  // ring-3 depth-2: read gs3[kt%3], write gs3[(kt+2)%3], in-flight kt+1,kt+2
  {
    floatx4 ga[2] = {{0.f,0.f,0.f,0.f},{0.f,0.f,0.f,0.f}};
    for (int kt = 0; kt < 32; ++kt) {
      if (kt < 30) {
        STAGE_F2(kt + 2, gs3[(kt + 2) % 3]);
        asm volatile("s_waitcnt vmcnt(4)" ::: "memory");   // stage kt landed
      } else if (kt == 30) {
        asm volatile("s_waitcnt vmcnt(0)" ::: "memory");
      }
      ushort* cur = gs3[kt % 3];
      short8 bfr = *(const short8*)&hbuf[fm * 1024 + (((kt * 4 + q) ^ (fm & 7)) * 8)];
      #pragma unroll
      for (int mt = 0; mt < 2; ++mt) {
        int r = mt * 16 + fm;
        short8 af = *(const short8*)&cur[r * 32 + (q ^ (r & 3)) * 8];
        ga[mt] = __builtin_amdgcn_mfma_f32_16x16x32_bf16(af, bfr, ga[mt], 0, 0, 0);
      }
    }
    #pragma unroll
    for (int mt = 0; mt < 2; ++mt) {
      #pragma unroll
      for (int r4 = 0; r4 < 4; ++r4) {
        int ch = wv * 32 + mt * 16 + q * 4 + r4;
        int n = (i0 + (fm >> 2)) * 56 + j0 + (fm & 3);
        outf[(size_t)ch * 3136 + n] = ga[mt][r4] + f2b[ch] + xv[mt][r4];
      }
    }
  }
#undef STAGE_P
#undef STAGE_F1
#undef STAGE_F2
}

// ---------------------------------------------------------------------------
extern "C" void kernel_launch(void* const* d_in, const int* in_sizes, int n_in,
                              void* d_out, int out_size, void* d_ws, size_t ws_size,
                              hipStream_t stream) {
  const float* x     = (const float*)d_in[0];
  const float* n1w   = (const float*)d_in[1];
  const float* n1b   = (const float*)d_in[2];
  const float* qkvw  = (const float*)d_in[3];
  const float* qkvb  = (const float*)d_in[4];
  const float* projw = (const float*)d_in[5];
  const float* projb = (const float*)d_in[6];
  const float* n2w   = (const float*)d_in[7];
  const float* n2b   = (const float*)d_in[8];
  const float* f1w   = (const float*)d_in[9];
  const float* f1b   = (const float*)d_in[10];
  const float* f2w   = (const float*)d_in[11];
  const float* f2b   = (const float*)d_in[12];

  char* ws = (char*)d_ws;
  ushort* wcat = (ushort*)(ws + 0);            // 786432 bf16
  ushort* t    = (ushort*)(ws + 4784128);      // 802816 bf16 (t1)
  ushort* qh   = (ushort*)(ws + 6389760);      // qkv [3136][768]

  const ushort* qw_bf = wcat;
  const ushort* pw_bf = wcat + 196608;
  const ushort* f1_bf = wcat + 262144;
  const ushort* f2_bf = wcat + 524288;
  float* outf = (float*)d_out;

  hipLaunchKernelGGL(prep_kernel, dim3(964), dim3(256), 0, stream,
                     x, n1w, n1b, qkvw, t, wcat);
  hipLaunchKernelGGL(qkv_kernel, dim3(12, 241), dim3(256), 0, stream,
                     t, qw_bf, qkvb, qh, projw, f1w, f2w, wcat);
  hipLaunchKernelGGL(attnmlp_kernel, dim3(196), dim3(512), 0, stream,
                     qh, pw_bf, projb, x, f1_bf, f1b, f2_bf, f2b,
                     n2w, n2b, outf);
}

// Round 15
// 122.743 us; speedup vs baseline: 1.0914x; 1.0226x over previous
//
#include <hip/hip_runtime.h>
#include <math.h>

// ---------------------------------------------------------------------------
// LocalTransformerBlock2d: B=1, C=256, H=W=56 (N=3136), 8 heads x d=32,
// 7x7 local window. fp32 in/out; bf16 MFMA GEMMs.
// 3 stream-ordered kernels:
//   prep(qw cvt + LN1T) -> qkv(+pw/f1/f2 cvt blocks) -> attnmlp
// R14 post-mortem: attnmlp pinned at ~41us across 5 rounds of pipelining
// tweaks -> the constraint is 2 waves/SIMD, not prefetch depth.
// R15: 1024 threads/block (16 waves, 4/SIMD), same 196 blocks, same LDS
// region map and barrier skeleton; per-wave work halved everywhere:
// scores 1 query/wave; PV 4ch/thread; proj 16ch/wave (1KB slabs, dbuf);
// fc1 2x32-col chunks (2KB slabs, dbuf); fc2 16ch/wave (1KB slabs, ring-3).
// ---------------------------------------------------------------------------

typedef unsigned int uint;
typedef unsigned short ushort;
typedef unsigned long long u64;
typedef __attribute__((ext_vector_type(8))) short short8;   // 8 bf16
typedef __attribute__((ext_vector_type(4))) float floatx4;  // MFMA acc
typedef __attribute__((ext_vector_type(4))) unsigned short ushort4v;

#define AS1(p) (const __attribute__((address_space(1))) void*)(p)
#define AS3(p) (__attribute__((address_space(3))) void*)(p)

__device__ __forceinline__ float bf2f(ushort u) {
  union { uint i; float f; } v; v.i = ((uint)u) << 16; return v.f;
}
__device__ __forceinline__ ushort f2bf(float f) {
  union { float f; uint i; } v; v.f = f;
  uint u = v.i;
  return (ushort)((u + 0x7fffu + ((u >> 16) & 1u)) >> 16);
}

// Stage a 64-row x 256-col bf16 panel into LDS with XOR swizzle (qkv kernel).
__device__ __forceinline__ void stage64(const ushort* src, int kstride,
                                        ushort* dstBase, int tid) {
  const int srow = tid >> 5;
  const int scb  = (tid & 31) ^ srow;
  const ushort* g = src + (size_t)srow * kstride + scb * 8;
  ushort* d = dstBase + tid * 8;
  #pragma unroll
  for (int r = 0; r < 8; ++r) {
    __builtin_amdgcn_global_load_lds(AS1(g), AS3(d), 16, 0, 0);
    g += 8 * kstride;
    d += 2048;
  }
}

__device__ __forceinline__ void compute64(const ushort* As, const ushort* Bs,
                                          int w, int lane, floatx4 acc[4]) {
  const int fm = lane & 15;
  const int q  = lane >> 4;
  const int swz = fm & 7;
  const int arow = (w * 16 + fm) * 256;
  #pragma unroll
  for (int kt = 0; kt < 8; ++kt) {
    const int blk = ((kt * 4 + q) ^ swz) * 8;
    short8 af = *(const short8*)&As[arow + blk];
    #pragma unroll
    for (int nt = 0; nt < 4; ++nt) {
      short8 bfr = *(const short8*)&Bs[(nt * 16 + fm) * 256 + blk];
      acc[nt] = __builtin_amdgcn_mfma_f32_16x16x32_bf16(af, bfr, acc[nt], 0, 0, 0);
    }
  }
}

// ---------------------------------------------------------------------------
// prep: blocks 0..195 LN1+transpose (16 px each); blocks 196..963 qkv-w cvt.
// ---------------------------------------------------------------------------
__global__ __launch_bounds__(256) void prep_kernel(
    const float* __restrict__ x, const float* __restrict__ n1w,
    const float* __restrict__ n1b, const float* __restrict__ qkvw,
    ushort* __restrict__ t1, ushort* __restrict__ wcat)
{
  const int tid = threadIdx.x;
  const int bid = blockIdx.x;
  if (bid >= 196) {
    int idx = (bid - 196) * 256 + tid;       // < 196608
    wcat[idx] = f2bf(qkvw[idx]);
    return;
  }
  __shared__ float tile[256 * 17];
  __shared__ float red[2][16][16];
  __shared__ float mu[16], rsv[16];
  const int n0 = bid * 16;
  const int px = tid & 15, grp = tid >> 4;
  #pragma unroll 4
  for (int it = 0; it < 16; ++it) {
    int c = it * 16 + grp;
    tile[c * 17 + px] = x[(size_t)c * 3136 + n0 + px];
  }
  __syncthreads();
  float s = 0.f, ss = 0.f;
  #pragma unroll
  for (int i = 0; i < 16; ++i) {
    float v = tile[(grp * 16 + i) * 17 + px];
    s += v; ss += v * v;
  }
  red[0][px][grp] = s; red[1][px][grp] = ss;
  __syncthreads();
  if (tid < 16) {
    float s2 = 0.f, ss2 = 0.f;
    #pragma unroll
    for (int g = 0; g < 16; ++g) { s2 += red[0][tid][g]; ss2 += red[1][tid][g]; }
    float m = s2 * (1.f / 256.f);
    float var = ss2 * (1.f / 256.f) - m * m;
    mu[tid] = m;
    rsv[tid] = rsqrtf(var + 1e-5f);
  }
  __syncthreads();
  const float wc = n1w[tid], bc = n1b[tid];
  #pragma unroll 4
  for (int p = 0; p < 16; ++p) {
    float v = tile[tid * 17 + p];
    t1[(size_t)(n0 + p) * 256 + tid] = f2bf((v - mu[p]) * rsv[p] * wc + bc);
  }
}

// ---------------------------------------------------------------------------
// qkv: grid (12, 241). y<49: GEMM [3136,256]@[768,256]^T + bias (q scaled).
// y>=49: cvt blocks for pw|f1|f2 (589824 elems), consumed by attnmlp.
// ---------------------------------------------------------------------------
__global__ __launch_bounds__(256, 2) void qkv_kernel(
    const ushort* __restrict__ A, const ushort* __restrict__ B,
    const float* __restrict__ bias, ushort* __restrict__ out,
    const float* __restrict__ projw, const float* __restrict__ f1w,
    const float* __restrict__ f2w, ushort* __restrict__ wcat)
{
  const int tid = threadIdx.x;
  if (blockIdx.y >= 49) {
    int c = (blockIdx.y - 49) * 12 + blockIdx.x;     // 0..2303
    int idx = c * 256 + tid;                         // < 589824
    float v;
    if (idx < 65536)        v = projw[idx];
    else if (idx < 327680)  v = f1w[idx - 65536];
    else                    v = f2w[idx - 327680];
    wcat[196608 + idx] = f2bf(v);
    return;
  }
  __shared__ ushort As[16384], Bs[16384];
  const int lane = tid & 63, w = tid >> 6;
  const int m0 = blockIdx.y * 64, n0 = blockIdx.x * 64;
  floatx4 acc[4] = {{0.f,0.f,0.f,0.f},{0.f,0.f,0.f,0.f},
                    {0.f,0.f,0.f,0.f},{0.f,0.f,0.f,0.f}};
  stage64(A + (size_t)m0 * 256, 256, As, tid);
  stage64(B + (size_t)n0 * 256, 256, Bs, tid);
  asm volatile("s_waitcnt vmcnt(0)" ::: "memory");
  __syncthreads();
  compute64(As, Bs, w, lane, acc);
  const int fm = lane & 15, q4 = (lane >> 4) * 4;
  #pragma unroll
  for (int nt = 0; nt < 4; ++nt)
    #pragma unroll
    for (int r = 0; r < 4; ++r) {
      int m = m0 + w * 16 + q4 + r;
      int n = n0 + nt * 16 + fm;
      float v = acc[nt][r] + bias[n];
      if (n < 256) v *= 0.17677669529663687f;   // 1/sqrt(32) on q
      out[(size_t)m * 768 + n] = f2bf(v);
    }
}

// ---------------------------------------------------------------------------
// attnmlp: 4x4 query tile per block (grid 196), 1024 threads (4 waves/SIMD).
// LDS (byte offsets; regions reused across phases):
//  attn: Kh@0 (52000) | Vh@52000 (51200) | pr@103200 f32 s67 (34304)
//        aas@137504 (8448) | pstat@145952 (2048) | stats@148000 (128)
//  proj: pslab@0 16wv x 2x1KB = 32KB (Kh dead) | x1s@103200 f32[16][264]
//  mlp : hbuf@0 (32768) | fslab@32768 16wv x 4KB = 64KB (ends 98304 < Vh end)
//        t2s@120096 [16][256]
// Per-wave ownership: scores q=wv | proj ch [16wv,16wv+16) | fc1 h-cols
// {32wv..+32, 32(wv+16)..+32} | fc2 ch [16wv,16wv+16).
// ---------------------------------------------------------------------------
#define AM_SMEM 148128

__global__ __launch_bounds__(1024, 1) void attnmlp_kernel(
    const ushort* __restrict__ qkv, const ushort* __restrict__ pw_bf,
    const float* __restrict__ projb, const float* __restrict__ x,
    const ushort* __restrict__ f1_bf, const float* __restrict__ f1b,
    const ushort* __restrict__ f2_bf, const float* __restrict__ f2b,
    const float* __restrict__ n2w, const float* __restrict__ n2b,
    float* __restrict__ outf)
{
  __shared__ __align__(16) char smem[AM_SMEM];
  ushort* Kh    = (ushort*)smem;
  ushort* Vh    = (ushort*)(smem + 52000);
  float*  pr    = (float*)(smem + 103200);       // [16*8][67]
  ushort* aas   = (ushort*)(smem + 137504);      // [16][264]
  ushort* pslab = (ushort*)smem;                 // proj slabs (Kh dead)
  float*  x1s   = (float*)(smem + 103200);       // [16][264] f32 (pr dead)
  ushort* hbuf  = (ushort*)smem;                 // [16][1024] (pslab dead)
  ushort* fslab = (ushort*)(smem + 32768);       // 16wv x 2048 ushorts
  ushort* t2s   = (ushort*)(smem + 120096);      // [16][256]
  float*  pstat = (float*)(smem + 145952);       // [16][16][2]
  float*  stats = (float*)(smem + 148000);       // [16][2]

  const int tid = threadIdx.x;
  const int wv = tid >> 6, lane = tid & 63;
  const int fm = lane & 15, q = lane >> 4;
  const int l4 = lane >> 2, lb = lane & 3;
  const int i0 = (blockIdx.x / 14) * 4, j0 = (blockIdx.x % 14) * 4;

  // ---- halo load (zero-fill out-of-image) ----
  for (int s = tid; s < 3200; s += 1024) {
    int p = s >> 5, ck = s & 31;
    int ii = i0 - 3 + p / 10, jj = j0 - 3 + p % 10;
    if (ii >= 0 && ii < 56 && jj >= 0 && jj < 56) {
      const ushort* kr = qkv + (size_t)(ii * 56 + jj) * 768 + 256 + ck * 8;
      short8 kv = *(const short8*)kr;
      u64 lo = ((const u64*)&kv)[0], hi = ((const u64*)&kv)[1];
      *(u64*)&Kh[p * 260 + ck * 8] = lo;
      *(u64*)&Kh[p * 260 + ck * 8 + 4] = hi;
      *(short8*)&Vh[p * 256 + ck * 8] = *(const short8*)(kr + 256);
    } else {
      *(u64*)&Kh[p * 260 + ck * 8] = 0ull;
      *(u64*)&Kh[p * 260 + ck * 8 + 4] = 0ull;
      short8 z = {0, 0, 0, 0, 0, 0, 0, 0};
      *(short8*)&Vh[p * 256 + ck * 8] = z;
    }
  }
  __syncthreads();

  // ---- scores + softmax: wave wv owns query p = wv ----
  {
    const int h = lane >> 3, mg = lane & 7;
    const int p = wv;
    const int qi = p >> 2, qj = p & 3;
    const int iq = i0 + qi, jq = j0 + qj;
    const ushort* qp = qkv + (size_t)(iq * 56 + jq) * 768 + h * 32;
    float qf[32];
    #pragma unroll
    for (int u = 0; u < 4; ++u) {
      short8 qv = *(const short8*)(qp + u * 8);
      #pragma unroll
      for (int e = 0; e < 8; ++e) qf[u * 8 + e] = bf2f((ushort)qv[e]);
    }
    float sv[7];
    float mx = -1e30f;
    #pragma unroll
    for (int k = 0; k < 7; ++k) {
      int m = mg + 8 * k;
      float s = -1e30f;
      if (m < 49) {
        int mi = m / 7, mj = m % 7;
        int ii = iq + mi - 3, jj = jq + mj - 3;
        if (ii >= 0 && ii < 56 && jj >= 0 && jj < 56) {
          int hrow = (qi + mi) * 10 + (qj + mj);
          const u64* k8 = (const u64*)&Kh[hrow * 260 + h * 32];
          float a = 0.f;
          #pragma unroll
          for (int u = 0; u < 8; ++u) {
            u64 kv = k8[u];
            #pragma unroll
            for (int e = 0; e < 4; ++e)
              a += qf[u * 4 + e] * bf2f((ushort)(kv >> (16 * e)));
          }
          s = a;
        }
      }
      sv[k] = s;
      mx = fmaxf(mx, s);
    }
    mx = fmaxf(mx, __shfl_xor(mx, 1));
    mx = fmaxf(mx, __shfl_xor(mx, 2));
    mx = fmaxf(mx, __shfl_xor(mx, 4));
    float sm = 0.f;
    #pragma unroll
    for (int k = 0; k < 7; ++k) { sv[k] = __expf(sv[k] - mx); sm += sv[k]; }
    sm += __shfl_xor(sm, 1);
    sm += __shfl_xor(sm, 2);
    sm += __shfl_xor(sm, 4);
    float inv = 1.f / sm;
    #pragma unroll
    for (int k = 0; k < 7; ++k) {
      int m = mg + 8 * k;
      pr[(p * 8 + h) * 67 + m] = sv[k] * inv;
    }
  }
  __syncthreads();     // Kh dead; pr visible

  // per-wave proj slab dbuf (2 x 1KB) in dead Kh region
  ushort* ps0 = pslab + wv * 1024;
  ushort* ps1 = ps0 + 512;
#define STAGE_P(kt, buf) do { \
    const ushort* g_ = pw_bf + (size_t)(wv * 16 + l4) * 256 + (kt) * 32 + (lb ^ (l4 & 3)) * 8; \
    __builtin_amdgcn_global_load_lds(AS1(g_), AS3((buf) + lane * 8), 16, 0, 0); \
  } while (0)
  STAGE_P(0, ps0);     // overlaps PV compute

  // ---- PV: thread = (query p = tid>>6, 4-ch group c4 = tid&63) ----
  {
    const int p = tid >> 6, c4 = tid & 63, hh = c4 >> 3;
    const int qi = p >> 2, qj = p & 3;
    float acc4[4] = {0, 0, 0, 0};
    #pragma unroll
    for (int mi = 0; mi < 7; ++mi)
      #pragma unroll
      for (int mj = 0; mj < 7; ++mj) {
        int m = mi * 7 + mj;
        int hrow = (qi + mi) * 10 + (qj + mj);
        float pm = pr[(p * 8 + hh) * 67 + m];
        u64 v4 = *(const u64*)&Vh[hrow * 256 + c4 * 4];
        #pragma unroll
        for (int e = 0; e < 4; ++e)
          acc4[e] += pm * bf2f((ushort)(v4 >> (16 * e)));
      }
    ushort4v o;
    #pragma unroll
    for (int e = 0; e < 4; ++e) o[e] = f2bf(acc4[e]);
    *(ushort4v*)&aas[p * 264 + c4 * 4] = o;
  }
  __syncthreads();     // aas visible; pr/Vh dead; proj stage 0 landed

  // ---- proj: wave wv -> out ch [16wv,16wv+16), all 16 px; resid from x ----
  {
    floatx4 pacc = {0.f, 0.f, 0.f, 0.f};
    for (int kt = 0; kt < 8; ++kt) {
      ushort* cur = (kt & 1) ? ps1 : ps0;
      ushort* nxt = (kt & 1) ? ps0 : ps1;
      if (kt < 7) {
        STAGE_P(kt + 1, nxt);
        asm volatile("s_waitcnt vmcnt(1)" ::: "memory");
      } else {
        asm volatile("s_waitcnt vmcnt(0)" ::: "memory");
      }
      short8 af = *(const short8*)&aas[fm * 264 + kt * 32 + q * 8];
      short8 bfr = *(const short8*)&cur[fm * 32 + ((q ^ (fm & 3)) * 8)];
      pacc = __builtin_amdgcn_mfma_f32_16x16x32_bf16(af, bfr, pacc, 0, 0, 0);
    }
    int ch = wv * 16 + fm;
    floatx4 rx = *(const floatx4*)(x + (size_t)ch * 3136 + (i0 + q) * 56 + j0);
    #pragma unroll
    for (int r = 0; r < 4; ++r) {
      int px = q * 4 + r;
      x1s[px * 264 + ch] = pacc[r] + projb[ch] + rx[r];
    }
  }
  // fc1 prologue: stage 0 into own fslab region (dead Vh; post-PV barrier)
  ushort* fs0 = fslab + wv * 2048;
  ushort* fs1 = fs0 + 1024;
#define STAGE_F1(c, kt, buf) do { \
    _Pragma("unroll") \
    for (int i_ = 0; i_ < 2; ++i_) { \
      int row_ = i_ * 16 + l4; \
      const ushort* g_ = f1_bf + (size_t)((c) * 32 + row_) * 256 + (kt) * 32 + (lb ^ (row_ & 3)) * 8; \
      __builtin_amdgcn_global_load_lds(AS1(g_), AS3((buf) + i_ * 512 + lane * 8), 16, 0, 0); \
    } } while (0)
  STAGE_F1(wv, 0, fs0);
  __syncthreads();     // x1s complete

  // ---- LN2 from x1s; residual kept in regs (matches fc2 acc layout) ----
  floatx4 xv = *(const floatx4*)&x1s[fm * 264 + wv * 16 + q * 4];
  {
    float s = xv[0] + xv[1] + xv[2] + xv[3];
    float ss = xv[0]*xv[0] + xv[1]*xv[1] + xv[2]*xv[2] + xv[3]*xv[3];
    s += __shfl_xor(s, 16); ss += __shfl_xor(ss, 16);
    s += __shfl_xor(s, 32); ss += __shfl_xor(ss, 32);
    if (lane < 16) { pstat[(wv * 16 + lane) * 2] = s; pstat[(wv * 16 + lane) * 2 + 1] = ss; }
  }
  __syncthreads();
  if (tid < 16) {
    float s2 = 0.f, ss2 = 0.f;
    #pragma unroll
    for (int ww = 0; ww < 16; ++ww) {
      s2 += pstat[(ww * 16 + tid) * 2];
      ss2 += pstat[(ww * 16 + tid) * 2 + 1];
    }
    float mu = s2 * (1.f / 256.f);
    float var = ss2 * (1.f / 256.f) - mu * mu;
    stats[tid * 2] = mu;
    stats[tid * 2 + 1] = rsqrtf(var + 1e-5f);
  }
  __syncthreads();
  {
    float mu = stats[fm * 2], rs = stats[fm * 2 + 1];
    int ch0 = wv * 16 + q * 4;
    ushort4v o;
    #pragma unroll
    for (int e = 0; e < 4; ++e)
      o[e] = f2bf((xv[e] - mu) * rs * n2w[ch0 + e] + n2b[ch0 + e]);
    int slot = ch0 >> 3;
    *(ushort4v*)&t2s[fm * 256 + ((slot ^ (fm & 7)) * 8) + (ch0 & 7)] = o;
  }
  // fc1 bias for this wave's 32-col chunks {wv, wv+16}
  float f1br[2][2];
  #pragma unroll
  for (int ci = 0; ci < 2; ++ci)
    #pragma unroll
    for (int nt = 0; nt < 2; ++nt)
      f1br[ci][nt] = f1b[(wv + ci * 16) * 32 + nt * 16 + fm];
  __syncthreads();     // t2s complete

  // ---- fc1: wave wv -> 2 chunks of 32 h-cols; gelu -> hbuf; dbuf-2 ----
  {
    floatx4 fa[2] = {{0.f,0.f,0.f,0.f},{0.f,0.f,0.f,0.f}};
    for (int sidx = 0; sidx < 16; ++sidx) {
      const int kt = sidx & 7;
      const int ci = sidx >> 3;
      ushort* cur = (sidx & 1) ? fs1 : fs0;
      ushort* nxt = (sidx & 1) ? fs0 : fs1;
      if (sidx < 15) {
        int s1 = sidx + 1;
        STAGE_F1(wv + (s1 >> 3) * 16, s1 & 7, nxt);
        asm volatile("s_waitcnt vmcnt(2)" ::: "memory");
      } else {
        asm volatile("s_waitcnt vmcnt(0)" ::: "memory");
      }
      short8 af = *(const short8*)&t2s[fm * 256 + (((kt * 4 + q) ^ (fm & 7)) * 8)];
      #pragma unroll
      for (int nt = 0; nt < 2; ++nt) {
        int r = nt * 16 + fm;
        short8 bfr = *(const short8*)&cur[r * 32 + (q ^ (r & 3)) * 8];
        fa[nt] = __builtin_amdgcn_mfma_f32_16x16x32_bf16(af, bfr, fa[nt], 0, 0, 0);
      }
      if (kt == 7) {
        #pragma unroll
        for (int nt = 0; nt < 2; ++nt) {
          int hc = (wv + ci * 16) * 32 + nt * 16 + fm;
          #pragma unroll
          for (int r4 = 0; r4 < 4; ++r4) {
            int prow = q * 4 + r4;
            float v = fa[nt][r4] + f1br[ci][nt];
            v = 0.5f * v * (1.0f + erff(v * 0.70710678118654752f));
            hbuf[prow * 1024 + (((hc >> 3) ^ (prow & 7)) * 8) + (hc & 7)] = f2bf(v);
            fa[nt][r4] = 0.f;
          }
        }
      }
    }
  }
  // fc2 ring-3 of 1KB slabs inside the wave's own fslab region
  ushort* gs3[3] = {fs0, fs0 + 512, fs0 + 1024};
#define STAGE_F2(kt, buf) do { \
    const ushort* g_ = f2_bf + (size_t)(wv * 16 + l4) * 1024 + (kt) * 32 + (lb ^ (l4 & 3)) * 8; \
    __builtin_amdgcn_global_load_lds(AS1(g_), AS3((buf) + lane * 8), 16, 0, 0); \
  } while (0)
  STAGE_F2(0, gs3[0]);
  STAGE_F2(1, gs3[1]);
  __syncthreads();     // hbuf complete (drains prologue stages too)

  // ---- fc2: wave wv -> out ch [16wv,16wv+16); residual from regs ----
  // ring-3 depth-2: read gs3[kt%3], write gs3[(kt+2)%3]; in-flight kt+1,kt+2
  {
    floatx4 ga = {0.f, 0.f, 0.f, 0.f};
    for (int kt = 0; kt < 32; ++kt) {
      if (kt < 30) {
        STAGE_F2(kt + 2, gs3[(kt + 2) % 3]);
        asm volatile("s_waitcnt vmcnt(2)" ::: "memory");   // stage kt landed
      } else if (kt == 30) {
        asm volatile("s_waitcnt vmcnt(0)" ::: "memory");
      }
      ushort* cur = gs3[kt % 3];
      short8 af = *(const short8*)&cur[fm * 32 + ((q ^ (fm & 3)) * 8)];
      short8 bfr = *(const short8*)&hbuf[fm * 1024 + (((kt * 4 + q) ^ (fm & 7)) * 8)];
      ga = __builtin_amdgcn_mfma_f32_16x16x32_bf16(af, bfr, ga, 0, 0, 0);
    }
    #pragma unroll
    for (int r4 = 0; r4 < 4; ++r4) {
      int ch = wv * 16 + q * 4 + r4;
      int n = (i0 + (fm >> 2)) * 56 + j0 + (fm & 3);
      outf[(size_t)ch * 3136 + n] = ga[r4] + f2b[ch] + xv[r4];
    }
  }
#undef STAGE_P
#undef STAGE_F1
#undef STAGE_F2
}

// ---------------------------------------------------------------------------
extern "C" void kernel_launch(void* const* d_in, const int* in_sizes, int n_in,
                              void* d_out, int out_size, void* d_ws, size_t ws_size,
                              hipStream_t stream) {
  const float* x     = (const float*)d_in[0];
  const float* n1w   = (const float*)d_in[1];
  const float* n1b   = (const float*)d_in[2];
  const float* qkvw  = (const float*)d_in[3];
  const float* qkvb  = (const float*)d_in[4];
  const float* projw = (const float*)d_in[5];
  const float* projb = (const float*)d_in[6];
  const float* n2w   = (const float*)d_in[7];
  const float* n2b   = (const float*)d_in[8];
  const float* f1w   = (const float*)d_in[9];
  const float* f1b   = (const float*)d_in[10];
  const float* f2w   = (const float*)d_in[11];
  const float* f2b   = (const float*)d_in[12];

  char* ws = (char*)d_ws;
  ushort* wcat = (ushort*)(ws + 0);            // 786432 bf16
  ushort* t    = (ushort*)(ws + 4784128);      // 802816 bf16 (t1)
  ushort* qh   = (ushort*)(ws + 6389760);      // qkv [3136][768]

  const ushort* qw_bf = wcat;
  const ushort* pw_bf = wcat + 196608;
  const ushort* f1_bf = wcat + 262144;
  const ushort* f2_bf = wcat + 524288;
  float* outf = (float*)d_out;

  hipLaunchKernelGGL(prep_kernel, dim3(964), dim3(256), 0, stream,
                     x, n1w, n1b, qkvw, t, wcat);
  hipLaunchKernelGGL(qkv_kernel, dim3(12, 241), dim3(256), 0, stream,
                     t, qw_bf, qkvb, qh, projw, f1w, f2w, wcat);
  hipLaunchKernelGGL(attnmlp_kernel, dim3(196), dim3(1024), 0, stream,
                     qh, pw_bf, projb, x, f1_bf, f1b, f2_bf, f2b,
                     n2w, n2b, outf);
}